// Round 1
// baseline (523.932 us; speedup 1.0000x reference)
//
#include <hip/hip_runtime.h>

#define DD 64

// ---- degree histogram (in-degree over col) ----
__global__ __launch_bounds__(256) void k_deg(const int* __restrict__ col,
                                             int* __restrict__ deg, int E) {
    int i = blockIdx.x * 256 + threadIdx.x;
    if (i < E) atomicAdd(&deg[col[i]], 1);
}

// dis[i] = rsqrt(deg[i] + 1)   (+1 = self loop; always > 0)
__global__ __launch_bounds__(256) void k_dis(const int* __restrict__ deg,
                                             float* __restrict__ dis, int n) {
    int i = blockIdx.x * 256 + threadIdx.x;
    if (i < n) dis[i] = rsqrtf((float)(deg[i] + 1));
}

// ---- H = X @ W  (X: [n,64], W: [64,64]) ----
// 256 threads/block, W staged in LDS, 4 rows per wave via shfl broadcast.
__global__ __launch_bounds__(256) void k_mm(const float* __restrict__ X,
                                            const float* __restrict__ W,
                                            float* __restrict__ H, int n) {
    __shared__ float Ws[4096];
    int t = threadIdx.x;
#pragma unroll
    for (int i = 0; i < 16; ++i) Ws[t + 256 * i] = W[t + 256 * i];
    __syncthreads();

    int lane = t & 63;
    int wv   = t >> 6;                    // 0..3
    int r0   = blockIdx.x * 16 + wv * 4;  // 4 rows per wave
    if (r0 >= n) return;

    float x0 = X[(size_t)r0 * DD + lane];
    float x1 = (r0 + 1 < n) ? X[(size_t)(r0 + 1) * DD + lane] : 0.f;
    float x2 = (r0 + 2 < n) ? X[(size_t)(r0 + 2) * DD + lane] : 0.f;
    float x3 = (r0 + 3 < n) ? X[(size_t)(r0 + 3) * DD + lane] : 0.f;

    float a0 = 0.f, a1 = 0.f, a2 = 0.f, a3 = 0.f;
#pragma unroll
    for (int k = 0; k < 64; ++k) {
        float w = Ws[k * 64 + lane];
        a0 = fmaf(__shfl(x0, k), w, a0);
        a1 = fmaf(__shfl(x1, k), w, a1);
        a2 = fmaf(__shfl(x2, k), w, a2);
        a3 = fmaf(__shfl(x3, k), w, a3);
    }
    H[(size_t)r0 * DD + lane] = a0;
    if (r0 + 1 < n) H[(size_t)(r0 + 1) * DD + lane] = a1;
    if (r0 + 2 < n) H[(size_t)(r0 + 2) * DD + lane] = a2;
    if (r0 + 3 < n) H[(size_t)(r0 + 3) * DD + lane] = a3;
}

// out[i][j] = b[j] + h[i][j] * dis[i]^2   (self-loop term + bias, non-atomic init)
__global__ __launch_bounds__(256) void k_init_out(const float* __restrict__ h,
                                                  const float* __restrict__ dis,
                                                  const float* __restrict__ b,
                                                  float* __restrict__ out, int n) {
    int i = blockIdx.x * 256 + threadIdx.x;
    if (i < n * DD) {
        int node = i >> 6, j = i & 63;
        float d = dis[node];
        out[i] = b[j] + h[i] * d * d;
    }
}

// one wave per edge: lane j handles feature j
__global__ __launch_bounds__(256) void k_scatter(const int* __restrict__ rowi,
                                                 const int* __restrict__ coli,
                                                 const float* __restrict__ dis,
                                                 const float* __restrict__ h,
                                                 float* __restrict__ out, int E) {
    int gid  = blockIdx.x * 256 + threadIdx.x;
    int e    = gid >> 6;
    int lane = gid & 63;
    if (e >= E) return;
    int r = rowi[e], c = coli[e];
    float nrm = dis[r] * dis[c];
    atomicAdd(&out[(size_t)c * DD + lane], h[(size_t)r * DD + lane] * nrm);
}

extern "C" void kernel_launch(void* const* d_in, const int* in_sizes, int n_in,
                              void* d_out, int out_size, void* d_ws, size_t ws_size,
                              hipStream_t stream) {
    const float* x  = (const float*)d_in[0];
    const int*   ei = (const int*)d_in[1];
    const float* W1 = (const float*)d_in[2];
    const float* b1 = (const float*)d_in[3];
    const float* W2 = (const float*)d_in[4];
    const float* b2 = (const float*)d_in[5];
    float* out = (float*)d_out;

    int n = in_sizes[0] / DD;     // 50000
    int E = in_sizes[1] / 2;      // 800000
    const int* rowi = ei;         // edge_index[0]
    const int* coli = ei + E;     // edge_index[1]

    char* ws = (char*)d_ws;
    int*   deg = (int*)ws;                                  // n ints
    float* dis = (float*)(ws + (size_t)256 * 1024);         // n floats
    float* h   = (float*)(ws + (size_t)512 * 1024);         // n*64 floats
    float* o1  = h + (size_t)n * DD;                        // n*64 floats

    int nb_e   = (E + 255) / 256;
    int nb_n   = (n + 255) / 256;
    int nb_mm  = (n + 15) / 16;
    int nb_el  = (n * DD + 255) / 256;
    int nb_sc  = (int)(((size_t)E * DD + 255) / 256);

    // normalization
    hipMemsetAsync(deg, 0, (size_t)n * sizeof(int), stream);
    k_deg<<<nb_e, 256, 0, stream>>>(coli, deg, E);
    k_dis<<<nb_n, 256, 0, stream>>>(deg, dis, n);

    // layer 1: o1 = scatter(x@W1) + b1
    k_mm<<<nb_mm, 256, 0, stream>>>(x, W1, h, n);
    k_init_out<<<nb_el, 256, 0, stream>>>(h, dis, b1, o1, n);
    k_scatter<<<nb_sc, 256, 0, stream>>>(rowi, coli, dis, h, o1, E);

    // layer 2: out = scatter(o1@W2) + b2
    k_mm<<<nb_mm, 256, 0, stream>>>(o1, W2, h, n);
    k_init_out<<<nb_el, 256, 0, stream>>>(h, dis, b2, out, n);
    k_scatter<<<nb_sc, 256, 0, stream>>>(rowi, coli, dis, h, out, E);
}

// Round 3
// 362.445 us; speedup vs baseline: 1.4456x; 1.4456x over previous
//
#include <hip/hip_runtime.h>

#define DD 64

// ---- degree histogram (in-degree over col) ----
__global__ __launch_bounds__(256) void k_deg(const int* __restrict__ col,
                                             int* __restrict__ deg, int E) {
    int i = blockIdx.x * 256 + threadIdx.x;
    if (i < E) atomicAdd(&deg[col[i]], 1);
}

// dis[i] = rsqrt(deg[i] + 1)   (+1 = self loop; always > 0)
__global__ __launch_bounds__(256) void k_dis(const int* __restrict__ deg,
                                             float* __restrict__ dis, int n) {
    int i = blockIdx.x * 256 + threadIdx.x;
    if (i < n) dis[i] = rsqrtf((float)(deg[i] + 1));
}

// ---- single-workgroup exclusive scan of deg -> off[n+1]; also cur[i]=off[i] ----
__global__ __launch_bounds__(1024) void k_scan(int* __restrict__ deg,   // in: counts, out: cursor copy
                                               int* __restrict__ off, int n) {
    __shared__ int wsum[16];
    __shared__ int carry;
    int t = threadIdx.x;
    if (t == 0) carry = 0;
    __syncthreads();
    int lane = t & 63, wv = t >> 6;
    for (int base = 0; base < n; base += 1024) {
        int i = base + t;
        int v = (i < n) ? deg[i] : 0;
        int s = v;
#pragma unroll
        for (int d = 1; d < 64; d <<= 1) {
            int u = __shfl_up(s, d);
            if (lane >= d) s += u;
        }
        if (lane == 63) wsum[wv] = s;
        __syncthreads();
        if (wv == 0 && lane < 16) {
            int ws = wsum[lane];
#pragma unroll
            for (int d = 1; d < 16; d <<= 1) {
                int u = __shfl_up(ws, d);
                if (lane >= d) ws += u;
            }
            wsum[lane] = ws;  // inclusive scan of wave sums
        }
        __syncthreads();
        int wexcl = (wv == 0) ? 0 : wsum[wv - 1];
        int excl = carry + wexcl + (s - v);
        if (i < n) { off[i] = excl; deg[i] = excl; }  // deg becomes the fill cursor
        __syncthreads();
        if (t == 0) carry += wsum[15];
        __syncthreads();
    }
    if (t == 0) off[n] = carry;
}

// ---- counting-sort fill: srt[] = source nodes grouped by destination ----
__global__ __launch_bounds__(256) void k_fill(const int* __restrict__ rowi,
                                              const int* __restrict__ coli,
                                              int* __restrict__ cur,
                                              int* __restrict__ srt, int E) {
    int i = blockIdx.x * 256 + threadIdx.x;
    if (i < E) {
        int c = coli[i];
        int p = atomicAdd(&cur[c], 1);
        srt[p] = rowi[i];
    }
}

// ---- H = (X @ W) * dis[row]  (X: [n,64], W: [64,64]) ----
__global__ __launch_bounds__(256) void k_mm(const float* __restrict__ X,
                                            const float* __restrict__ W,
                                            const float* __restrict__ dis,
                                            float* __restrict__ H, int n) {
    __shared__ float Ws[4096];
    int t = threadIdx.x;
#pragma unroll
    for (int i = 0; i < 16; ++i) Ws[t + 256 * i] = W[t + 256 * i];
    __syncthreads();

    int lane = t & 63;
    int wv   = t >> 6;
    int r0   = blockIdx.x * 16 + wv * 4;
    if (r0 >= n) return;

    float x0 = X[(size_t)r0 * DD + lane];
    float x1 = (r0 + 1 < n) ? X[(size_t)(r0 + 1) * DD + lane] : 0.f;
    float x2 = (r0 + 2 < n) ? X[(size_t)(r0 + 2) * DD + lane] : 0.f;
    float x3 = (r0 + 3 < n) ? X[(size_t)(r0 + 3) * DD + lane] : 0.f;

    float a0 = 0.f, a1 = 0.f, a2 = 0.f, a3 = 0.f;
#pragma unroll
    for (int k = 0; k < 64; ++k) {
        float w = Ws[k * 64 + lane];
        a0 = fmaf(__shfl(x0, k), w, a0);
        a1 = fmaf(__shfl(x1, k), w, a1);
        a2 = fmaf(__shfl(x2, k), w, a2);
        a3 = fmaf(__shfl(x3, k), w, a3);
    }
    H[(size_t)r0 * DD + lane] = a0 * dis[r0];
    if (r0 + 1 < n) H[(size_t)(r0 + 1) * DD + lane] = a1 * dis[r0 + 1];
    if (r0 + 2 < n) H[(size_t)(r0 + 2) * DD + lane] = a2 * dis[r0 + 2];
    if (r0 + 3 < n) H[(size_t)(r0 + 3) * DD + lane] = a3 * dis[r0 + 3];
}

// ---- aggregate: out[c] = b + dis[c] * (hs[c] + sum_{r in N(c)} hs[r]) ----
// one wave per destination node; lane j = feature j
__global__ __launch_bounds__(256) void k_agg(const int* __restrict__ off,
                                             const int* __restrict__ srt,
                                             const float* __restrict__ dis,
                                             const float* __restrict__ hs,
                                             const float* __restrict__ b,
                                             float* __restrict__ out, int n) {
    int gid  = blockIdx.x * 256 + threadIdx.x;
    int c    = gid >> 6;
    int lane = gid & 63;
    if (c >= n) return;

    int s = off[c], e = off[c + 1];
    float acc = hs[(size_t)c * DD + lane];          // self-loop term
    for (int base = s; base < e; base += 64) {
        int cnt = min(64, e - base);
        int rl = (lane < cnt) ? srt[base + lane] : 0;  // coalesced edge-list read
        for (int k = 0; k < cnt; ++k) {
            int r = __shfl(rl, k);
            acc += hs[(size_t)r * DD + lane];          // coalesced 256B gather
        }
    }
    out[(size_t)c * DD + lane] = b[lane] + dis[c] * acc;
}

extern "C" void kernel_launch(void* const* d_in, const int* in_sizes, int n_in,
                              void* d_out, int out_size, void* d_ws, size_t ws_size,
                              hipStream_t stream) {
    const float* x  = (const float*)d_in[0];
    const int*   ei = (const int*)d_in[1];
    const float* W1 = (const float*)d_in[2];
    const float* b1 = (const float*)d_in[3];
    const float* W2 = (const float*)d_in[4];
    const float* b2 = (const float*)d_in[5];
    float* out = (float*)d_out;

    int n = in_sizes[0] / DD;     // 50000
    int E = in_sizes[1] / 2;      // 800000
    const int* rowi = ei;         // edge_index[0] (source)
    const int* coli = ei + E;     // edge_index[1] (destination)

    char* ws = (char*)d_ws;
    int*   deg = (int*)ws;                                   // n ints (becomes cursor)
    int*   off = (int*)(ws + (size_t)256 * 1024);            // n+1 ints
    float* dis = (float*)(ws + (size_t)512 * 1024);          // n floats
    int*   srt = (int*)(ws + (size_t)768 * 1024);            // E ints (3.2 MB)
    float* h   = (float*)(ws + (size_t)4096 * 1024);         // n*64 floats (12.8 MB)
    float* o1  = out;                                        // layer-1 output lives in d_out

    int nb_e  = (E + 255) / 256;
    int nb_n  = (n + 255) / 256;
    int nb_mm = (n + 15) / 16;
    int nb_ag = (int)(((size_t)n * 64 + 255) / 256);   // one wave (64 threads) per node

    // ---- build normalization + CSR (shared by both layers) ----
    hipMemsetAsync(deg, 0, (size_t)n * sizeof(int), stream);
    k_deg <<<nb_e, 256, 0, stream>>>(coli, deg, E);
    k_dis <<<nb_n, 256, 0, stream>>>(deg, dis, n);
    k_scan<<<1, 1024, 0, stream>>>(deg, off, n);
    k_fill<<<nb_e, 256, 0, stream>>>(rowi, coli, deg, srt, E);

    // ---- layer 1 ----
    k_mm <<<nb_mm, 256, 0, stream>>>(x, W1, dis, h, n);
    k_agg<<<nb_ag, 256, 0, stream>>>(off, srt, dis, h, b1, o1, n);

    // ---- layer 2 ----
    k_mm <<<nb_mm, 256, 0, stream>>>(o1, W2, dis, h, n);
    k_agg<<<nb_ag, 256, 0, stream>>>(off, srt, dis, h, b2, out, n);
}

// Round 4
// 243.042 us; speedup vs baseline: 2.1557x; 1.4913x over previous
//
#include <hip/hip_runtime.h>

#define DD 64

// ---- degree histogram (in-degree over col) ----
__global__ __launch_bounds__(256) void k_deg(const int* __restrict__ col,
                                             int* __restrict__ deg, int E) {
    int i = blockIdx.x * 256 + threadIdx.x;
    if (i < E) atomicAdd(&deg[col[i]], 1);
}

// dis[i] = rsqrt(deg[i] + 1)   (+1 = self loop; always > 0)
__global__ __launch_bounds__(256) void k_dis(const int* __restrict__ deg,
                                             float* __restrict__ dis, int n) {
    int i = blockIdx.x * 256 + threadIdx.x;
    if (i < n) dis[i] = rsqrtf((float)(deg[i] + 1));
}

// ---- single-workgroup exclusive scan of deg -> off[n+1]; also cur[i]=off[i] ----
__global__ __launch_bounds__(1024) void k_scan(int* __restrict__ deg,
                                               int* __restrict__ off, int n) {
    __shared__ int wsum[16];
    __shared__ int carry;
    int t = threadIdx.x;
    if (t == 0) carry = 0;
    __syncthreads();
    int lane = t & 63, wv = t >> 6;
    for (int base = 0; base < n; base += 1024) {
        int i = base + t;
        int v = (i < n) ? deg[i] : 0;
        int s = v;
#pragma unroll
        for (int d = 1; d < 64; d <<= 1) {
            int u = __shfl_up(s, d);
            if (lane >= d) s += u;
        }
        if (lane == 63) wsum[wv] = s;
        __syncthreads();
        if (wv == 0 && lane < 16) {
            int ws = wsum[lane];
#pragma unroll
            for (int d = 1; d < 16; d <<= 1) {
                int u = __shfl_up(ws, d);
                if (lane >= d) ws += u;
            }
            wsum[lane] = ws;
        }
        __syncthreads();
        int wexcl = (wv == 0) ? 0 : wsum[wv - 1];
        int excl = carry + wexcl + (s - v);
        if (i < n) { off[i] = excl; deg[i] = excl; }
        __syncthreads();
        if (t == 0) carry += wsum[15];
        __syncthreads();
    }
    if (t == 0) off[n] = carry;
}

// ---- counting-sort fill: srt[] = source nodes grouped by destination ----
__global__ __launch_bounds__(256) void k_fill(const int* __restrict__ rowi,
                                              const int* __restrict__ coli,
                                              int* __restrict__ cur,
                                              int* __restrict__ srt, int E) {
    int i = blockIdx.x * 256 + threadIdx.x;
    if (i < E) {
        int c = coli[i];
        int p = atomicAdd(&cur[c], 1);
        srt[p] = rowi[i];
    }
}

// ---- H = (X @ W) * dis[row] ----
// lane = row; W values are wave-uniform -> SGPR (s_load) -> v_fmac v,s,v.
// 2-way column split: blockIdx bit0 selects jbase in {0,32}; 32 acc VGPRs.
__global__ __launch_bounds__(64) void k_mm(const float* __restrict__ X,
                                           const float* __restrict__ W,
                                           const float* __restrict__ dis,
                                           float* __restrict__ H, int n) {
    int lane  = threadIdx.x;
    int tile  = blockIdx.x >> 1;
    int jbase = (blockIdx.x & 1) * 32;
    int r     = tile * 64 + lane;
    int rc    = min(r, n - 1);

    const float4* X4 = (const float4*)X;
    float acc[32];
#pragma unroll
    for (int j = 0; j < 32; ++j) acc[j] = 0.f;

#pragma unroll 1
    for (int kc = 0; kc < 16; ++kc) {
        float4 xv = X4[(size_t)rc * 16 + kc];
        const float* W0 = W + (kc * 4) * 64 + jbase;   // uniform address
#pragma unroll
        for (int u = 0; u < 4; ++u) {
            float xk = (u == 0) ? xv.x : (u == 1) ? xv.y : (u == 2) ? xv.z : xv.w;
            const float* Wk = W0 + u * 64;
#pragma unroll
            for (int j = 0; j < 32; ++j)
                acc[j] = fmaf(xk, Wk[j], acc[j]);
        }
    }
    if (r < n) {
        float d = dis[r];
        float4* H4 = (float4*)(H + (size_t)r * DD + jbase);
#pragma unroll
        for (int q = 0; q < 8; ++q) {
            float4 o;
            o.x = acc[q * 4 + 0] * d;
            o.y = acc[q * 4 + 1] * d;
            o.z = acc[q * 4 + 2] * d;
            o.w = acc[q * 4 + 3] * d;
            H4[q] = o;
        }
    }
}

// ---- aggregate: out[c] = b + dis[c] * (hs[c] + sum_{r in N(c)} hs[r]) ----
// one wave per node; edge indices via scalar loads (uniform addresses), 8-deep MLP
__global__ __launch_bounds__(256) void k_agg(const int* __restrict__ off,
                                             const int* __restrict__ srt,
                                             const float* __restrict__ dis,
                                             const float* __restrict__ hs,
                                             const float* __restrict__ b,
                                             float* __restrict__ out, int n) {
    int lane = threadIdx.x & 63;
    int c = __builtin_amdgcn_readfirstlane(blockIdx.x * 4 + (threadIdx.x >> 6));
    if (c >= n) return;

    int s = __builtin_amdgcn_readfirstlane(off[c]);
    int e = __builtin_amdgcn_readfirstlane(off[c + 1]);

    float acc = hs[(size_t)c * DD + lane];   // self-loop term
    int p = s;
    for (; p + 8 <= e; p += 8) {
        int r0 = srt[p + 0], r1 = srt[p + 1], r2 = srt[p + 2], r3 = srt[p + 3];
        int r4 = srt[p + 4], r5 = srt[p + 5], r6 = srt[p + 6], r7 = srt[p + 7];
        float v0 = hs[(size_t)r0 * DD + lane];
        float v1 = hs[(size_t)r1 * DD + lane];
        float v2 = hs[(size_t)r2 * DD + lane];
        float v3 = hs[(size_t)r3 * DD + lane];
        float v4 = hs[(size_t)r4 * DD + lane];
        float v5 = hs[(size_t)r5 * DD + lane];
        float v6 = hs[(size_t)r6 * DD + lane];
        float v7 = hs[(size_t)r7 * DD + lane];
        acc += ((v0 + v1) + (v2 + v3)) + ((v4 + v5) + (v6 + v7));
    }
    for (; p < e; ++p) acc += hs[(size_t)srt[p] * DD + lane];

    out[(size_t)c * DD + lane] = b[lane] + dis[c] * acc;
}

extern "C" void kernel_launch(void* const* d_in, const int* in_sizes, int n_in,
                              void* d_out, int out_size, void* d_ws, size_t ws_size,
                              hipStream_t stream) {
    const float* x  = (const float*)d_in[0];
    const int*   ei = (const int*)d_in[1];
    const float* W1 = (const float*)d_in[2];
    const float* b1 = (const float*)d_in[3];
    const float* W2 = (const float*)d_in[4];
    const float* b2 = (const float*)d_in[5];
    float* out = (float*)d_out;

    int n = in_sizes[0] / DD;     // 50000
    int E = in_sizes[1] / 2;      // 800000
    const int* rowi = ei;         // edge_index[0] (source)
    const int* coli = ei + E;     // edge_index[1] (destination)

    char* ws = (char*)d_ws;
    int*   deg = (int*)ws;                                   // n ints (becomes cursor)
    int*   off = (int*)(ws + (size_t)256 * 1024);            // n+1 ints
    float* dis = (float*)(ws + (size_t)512 * 1024);          // n floats
    int*   srt = (int*)(ws + (size_t)768 * 1024);            // E ints (3.2 MB)
    float* h   = (float*)(ws + (size_t)4096 * 1024);         // n*64 floats (12.8 MB)
    float* o1  = out;                                        // layer-1 output lives in d_out

    int nb_e  = (E + 255) / 256;
    int nb_n  = (n + 255) / 256;
    int nb_mm = ((n + 63) / 64) * 2;                 // 1 wave/block, 2-way j-split
    int nb_ag = (n + 3) / 4;                         // 4 waves/block, 1 wave per node

    // ---- build normalization + CSR (shared by both layers) ----
    hipMemsetAsync(deg, 0, (size_t)n * sizeof(int), stream);
    k_deg <<<nb_e, 256, 0, stream>>>(coli, deg, E);
    k_dis <<<nb_n, 256, 0, stream>>>(deg, dis, n);
    k_scan<<<1, 1024, 0, stream>>>(deg, off, n);
    k_fill<<<nb_e, 256, 0, stream>>>(rowi, coli, deg, srt, E);

    // ---- layer 1 ----
    k_mm <<<nb_mm, 64, 0, stream>>>(x, W1, dis, h, n);
    k_agg<<<nb_ag, 256, 0, stream>>>(off, srt, dis, h, b1, o1, n);

    // ---- layer 2 ----
    k_mm <<<nb_mm, 64, 0, stream>>>(o1, W2, dis, h, n);
    k_agg<<<nb_ag, 256, 0, stream>>>(off, srt, dis, h, b2, out, n);
}